// Round 1
// baseline (1040.832 us; speedup 1.0000x reference)
//
#include <hip/hip_runtime.h>
#include <math.h>

#define N_NODES 661
#define N_GRAPH 128
#define DEG 8
#define EPG (N_NODES*DEG)          // 5288 edges per graph per matrix
#define NTOT (N_NODES*N_GRAPH)     // 84608 nodes
#define FDIM 64
#define NF ((size_t)NTOT*FDIM)     // 5,414,912 elements per [n,64] array

// ---------------------------------------------------------------------------
// Kernel A: per-(graph,matrix) CSR build in LDS + gather SpMM (no global atomics)
// ws layout: [eG, fG, eB, fB, e1, f1, e2, f2], each NF floats
// ---------------------------------------------------------------------------
__global__ __launch_bounds__(256) void spmm_all(
    const float* __restrict__ e, const float* __restrict__ f,
    const int* __restrict__ rG, const int* __restrict__ cG, const float* __restrict__ vG,
    const int* __restrict__ rB, const int* __restrict__ cB, const float* __restrict__ vB,
    const int* __restrict__ r1, const int* __restrict__ c1, const float* __restrict__ v1,
    const int* __restrict__ r2, const int* __restrict__ c2, const float* __restrict__ v2,
    float* __restrict__ ws)
{
    __shared__ int   scount[N_NODES];
    __shared__ int   soffs[N_NODES+1];
    __shared__ int   scursor[N_NODES];
    __shared__ int   scol[EPG];
    __shared__ float sval[EPG];
    __shared__ int   spart[256];

    int bid = blockIdx.x;
    int g = bid & 127;
    int m = bid >> 7;
    const int*   rows = (m==0)?rG:(m==1)?rB:(m==2)?r1:r2;
    const int*   cols = (m==0)?cG:(m==1)?cB:(m==2)?c1:c2;
    const float* vals = (m==0)?vG:(m==1)?vB:(m==2)?v1:v2;
    float* out_e = ws + (size_t)(2*m)*NF;
    float* out_f = out_e + NF;

    int tid = threadIdx.x;
    int ebase = g*EPG;
    int gbase = g*N_NODES;

    for (int i = tid; i < N_NODES; i += 256) scount[i] = 0;
    __syncthreads();
    for (int i = tid; i < EPG; i += 256)
        atomicAdd(&scount[rows[ebase+i] - gbase], 1);
    __syncthreads();

    // prefix scan over 661 counts: 3-per-thread chunks + serial scan of 256 partials
    int c0 = tid*3;
    int ps = 0;
    #pragma unroll
    for (int j = 0; j < 3; ++j) { int i = c0+j; if (i < N_NODES) ps += scount[i]; }
    spart[tid] = ps;
    __syncthreads();
    if (tid == 0) {
        int run = 0;
        for (int i = 0; i < 256; ++i) { int t = spart[i]; spart[i] = run; run += t; }
        soffs[N_NODES] = EPG;
    }
    __syncthreads();
    int run = spart[tid];
    #pragma unroll
    for (int j = 0; j < 3; ++j) {
        int i = c0+j;
        if (i < N_NODES) { soffs[i] = run; scursor[i] = run; run += scount[i]; }
    }
    __syncthreads();
    for (int i = tid; i < EPG; i += 256) {
        int r = rows[ebase+i] - gbase;
        int pos = atomicAdd(&scursor[r], 1);
        scol[pos] = cols[ebase+i];   // global column index
        sval[pos] = vals[ebase+i];
    }
    __syncthreads();

    // gather SpMM: wave per row, lane = feature
    int lane = tid & 63, wv = tid >> 6;
    for (int r = wv; r < N_NODES; r += 4) {
        int s = soffs[r], t = soffs[r+1];
        float ae = 0.f, af = 0.f;
        for (int k = s; k < t; ++k) {
            int cc = scol[k];
            float v = sval[k];
            ae = fmaf(v, e[(size_t)cc*FDIM + lane], ae);
            af = fmaf(v, f[(size_t)cc*FDIM + lane], af);
        }
        size_t o = (size_t)(gbase + r)*FDIM + lane;
        out_e[o] = ae;
        out_f[o] = af;
    }
}

// ---------------------------------------------------------------------------
// shared elementwise math (matches reference formulas)
// ---------------------------------------------------------------------------
__device__ __forceinline__ void node_math(
    float ev, float fv, float gd, float bd, float pd, float qd,
    float eGv, float fGv, float eBv, float fBv,
    float& e3v, float& nev, float& f3v, float& nfv)
{
    float invb = 1.0f/(ev*ev + fv*fv + 0.1f);
    float alpha = (pd*ev + qd*fv)*invb - eGv - fBv;
    float beta  = (qd*ev - pd*fv)*invb + fGv + eBv;
    float invg = 1.0f/(gd*gd + bd*bd);
    e3v = (alpha*gd + beta*bd)*invg;
    f3v = (beta*gd - alpha*bd)*invg;
    float bb1 = eGv - fBv, bb2 = fGv + eBv;
    float vv = ev*ev + fv*fv;
    float P_ = pd - vv*gd, Q_ = qd + vv*bd;
    nev = (P_*bb1 + Q_*bb2)*invg;
    nfv = (P_*bb2 - Q_*bb1)*invg;
}

// ---------------------------------------------------------------------------
// Kernel B1: per-(graph, quarter) partial sums of the 8 attention dot products
// partials: [512][8]
// ---------------------------------------------------------------------------
__global__ __launch_bounds__(256) void attn_partial(
    const float* __restrict__ e, const float* __restrict__ f,
    const float* __restrict__ Gd, const float* __restrict__ Bd,
    const float* __restrict__ Pd, const float* __restrict__ Qd,
    const float* __restrict__ spmm, const float* __restrict__ w_ae,
    const float* __restrict__ w_af, float* __restrict__ partials)
{
    int bid = blockIdx.x;
    int g = bid >> 2, q = bid & 3;
    int tid = threadIdx.x, lane = tid & 63, chunk = tid >> 6;
    int cg = q*4 + chunk;   // 0..15

    const float* eG = spmm + 0*NF; const float* fG = spmm + 1*NF;
    const float* eB = spmm + 2*NF; const float* fB = spmm + 3*NF;
    const float* e1 = spmm + 4*NF; const float* f1 = spmm + 5*NF;
    const float* e2 = spmm + 6*NF; const float* f2 = spmm + 7*NF;

    float acc[8];
    #pragma unroll
    for (int j = 0; j < 8; ++j) acc[j] = 0.f;

    for (int r = cg; r < N_NODES; r += 16) {
        int node = g*N_NODES + r;
        size_t idx = (size_t)node*FDIM + lane;
        float ev = e[idx], fv = f[idx];
        float gd = Gd[node], bd = Bd[node], pd = Pd[node], qd = Qd[node];
        float eGv = eG[idx], fGv = fG[idx], eBv = eB[idx], fBv = fB[idx];
        float e3v, nev, f3v, nfv;
        node_math(ev, fv, gd, bd, pd, qd, eGv, fGv, eBv, fBv, e3v, nev, f3v, nfv);
        acc[0] += e3v; acc[1] += nev; acc[2] += e1[idx]; acc[3] += e2[idx];
        acc[4] += f3v; acc[5] += nfv; acc[6] += f1[idx]; acc[7] += f2[idx];
    }
    float wa = w_ae[lane], wf = w_af[lane];
    #pragma unroll
    for (int j = 0; j < 4; ++j) acc[j] *= wa;
    #pragma unroll
    for (int j = 4; j < 8; ++j) acc[j] *= wf;

    __shared__ float red[8];
    if (tid < 8) red[tid] = 0.f;
    __syncthreads();
    #pragma unroll
    for (int j = 0; j < 8; ++j) {
        float v = acc[j];
        for (int off = 32; off > 0; off >>= 1) v += __shfl_down(v, off);
        if (lane == 0) atomicAdd(&red[j], v);
    }
    __syncthreads();
    if (tid < 8) partials[(size_t)bid*8 + tid] = red[tid];
}

// ---------------------------------------------------------------------------
// Kernel B2: finalize attention weights: att[g][0..3]=a_e, [4..7]=a_f
// ---------------------------------------------------------------------------
__global__ void attn_final(const float* __restrict__ partials,
                           const float* __restrict__ b_ae, const float* __restrict__ b_af,
                           float* __restrict__ att)
{
    int g = threadIdx.x;
    if (g >= N_GRAPH) return;
    float s[8];
    #pragma unroll
    for (int j = 0; j < 8; ++j) {
        float t = 0.f;
        for (int q = 0; q < 4; ++q) t += partials[(size_t)(g*4+q)*8 + j];
        s[j] = t;
    }
    float ae[4], af[4], se = 1e-4f, sf = 1e-4f;
    float bae = b_ae[0], baf = b_af[0];
    #pragma unroll
    for (int j = 0; j < 4; ++j) {
        float x = s[j]*(1.0f/N_NODES) + bae;
        ae[j] = 1.0f/(1.0f + expf(-x)); se += ae[j];
        float y = s[4+j]*(1.0f/N_NODES) + baf;
        af[j] = 1.0f/(1.0f + expf(-y)); sf += af[j];
    }
    #pragma unroll
    for (int j = 0; j < 4; ++j) {
        att[g*8 + j]     = ae[j]/se;
        att[g*8 + 4 + j] = af[j]/sf;
    }
}

// ---------------------------------------------------------------------------
// Kernel C: recompute elementwise, build cat vectors in LDS, fused GEMM+tanh
// 16 nodes per block; out = [e_new (NF) | f_new (NF)]
// ---------------------------------------------------------------------------
#define STR 324  // 320 padded to 16B-aligned rows (324*4 = 1296 bytes)
__global__ __launch_bounds__(256) void final_fused(
    const float* __restrict__ e, const float* __restrict__ f,
    const float* __restrict__ Gd, const float* __restrict__ Bd,
    const float* __restrict__ Pd, const float* __restrict__ Qd,
    const float* __restrict__ spmm, const float* __restrict__ att,
    const float* __restrict__ W1, const float* __restrict__ bv1,
    const float* __restrict__ W2, const float* __restrict__ bv2,
    float* __restrict__ out)
{
    __shared__ __align__(16) float cat_e[16*STR];
    __shared__ __align__(16) float cat_f[16*STR];

    int tid = threadIdx.x, lane = tid & 63, chunk = tid >> 6;
    int node0 = blockIdx.x * 16;

    const float* eG = spmm + 0*NF; const float* fG = spmm + 1*NF;
    const float* eB = spmm + 2*NF; const float* fB = spmm + 3*NF;
    const float* e1 = spmm + 4*NF; const float* f1 = spmm + 5*NF;
    const float* e2 = spmm + 6*NF; const float* f2 = spmm + 7*NF;

    #pragma unroll
    for (int round = 0; round < 4; ++round) {
        int ni = round*4 + chunk;
        int node = node0 + ni;
        int g = node / N_NODES;
        size_t idx = (size_t)node*FDIM + lane;
        float ev = e[idx], fv = f[idx];
        float gd = Gd[node], bd = Bd[node], pd = Pd[node], qd = Qd[node];
        float eGv = eG[idx], fGv = fG[idx], eBv = eB[idx], fBv = fB[idx];
        float e1v = e1[idx], f1v = f1[idx], e2v = e2[idx], f2v = f2[idx];
        float e3v, nev, f3v, nfv;
        node_math(ev, fv, gd, bd, pd, qd, eGv, fGv, eBv, fBv, e3v, nev, f3v, nfv);
        float* ce = &cat_e[ni*STR];
        float* cf = &cat_f[ni*STR];
        ce[lane]       = e3v*att[g*8+0];
        ce[64+lane]    = nev*att[g*8+1];
        ce[128+lane]   = e1v*att[g*8+2];
        ce[192+lane]   = e2v*att[g*8+3];
        ce[256+lane]   = ev;
        cf[lane]       = f3v*att[g*8+4];
        cf[64+lane]    = nfv*att[g*8+5];
        cf[128+lane]   = f1v*att[g*8+6];
        cf[192+lane]   = f2v*att[g*8+7];
        cf[256+lane]   = fv;
    }
    __syncthreads();

    // GEMM: thread = (ofeat=lane, 4 nodes of this chunk); W rows via float4
    float ae[4], af[4];
    #pragma unroll
    for (int j = 0; j < 4; ++j) { ae[j] = bv1[lane]; af[j] = bv2[lane]; }

    for (int k4 = 0; k4 < 80; ++k4) {
        float4 w1 = *(const float4*)(W1 + (size_t)lane*320 + k4*4);
        float4 w2 = *(const float4*)(W2 + (size_t)lane*320 + k4*4);
        #pragma unroll
        for (int j = 0; j < 4; ++j) {
            int ni = chunk*4 + j;
            float4 cev = *(const float4*)(&cat_e[ni*STR + k4*4]);
            float4 cfv = *(const float4*)(&cat_f[ni*STR + k4*4]);
            ae[j] = fmaf(cev.x, w1.x, fmaf(cev.y, w1.y, fmaf(cev.z, w1.z, fmaf(cev.w, w1.w, ae[j]))));
            af[j] = fmaf(cfv.x, w2.x, fmaf(cfv.y, w2.y, fmaf(cfv.z, w2.z, fmaf(cfv.w, w2.w, af[j]))));
        }
    }
    #pragma unroll
    for (int j = 0; j < 4; ++j) {
        int node = node0 + chunk*4 + j;
        out[(size_t)node*FDIM + lane]      = tanhf(ae[j]);
        out[NF + (size_t)node*FDIM + lane] = tanhf(af[j]);
    }
}

// ---------------------------------------------------------------------------
extern "C" void kernel_launch(void* const* d_in, const int* in_sizes, int n_in,
                              void* d_out, int out_size, void* d_ws, size_t ws_size,
                              hipStream_t stream) {
    (void)in_sizes; (void)n_in; (void)out_size; (void)ws_size;
    const float* e     = (const float*)d_in[0];
    const float* f     = (const float*)d_in[1];
    const int*   rowsG = (const int*)d_in[2];
    const int*   colsG = (const int*)d_in[3];
    const float* valsG = (const float*)d_in[4];
    const int*   rowsB = (const int*)d_in[5];
    const int*   colsB = (const int*)d_in[6];
    const float* valsB = (const float*)d_in[7];
    const int*   rows1 = (const int*)d_in[8];
    const int*   cols1 = (const int*)d_in[9];
    const float* vals1 = (const float*)d_in[10];
    const int*   rows2 = (const int*)d_in[11];
    const int*   cols2 = (const int*)d_in[12];
    const float* vals2 = (const float*)d_in[13];
    const float* G_d   = (const float*)d_in[14];
    const float* B_d   = (const float*)d_in[15];
    const float* Pd    = (const float*)d_in[16];
    const float* Qd    = (const float*)d_in[17];
    const float* W1    = (const float*)d_in[18];
    const float* b1    = (const float*)d_in[19];
    const float* W2    = (const float*)d_in[20];
    const float* b2    = (const float*)d_in[21];
    const float* w_ae  = (const float*)d_in[22];
    const float* b_ae  = (const float*)d_in[23];
    const float* w_af  = (const float*)d_in[24];
    const float* b_af  = (const float*)d_in[25];

    float* ws       = (float*)d_ws;
    float* spmm     = ws;                       // 8*NF floats
    float* partials = ws + 8*NF;                // 512*8
    float* att      = partials + 512*8;         // 128*8

    spmm_all<<<dim3(512), dim3(256), 0, stream>>>(
        e, f, rowsG, colsG, valsG, rowsB, colsB, valsB,
        rows1, cols1, vals1, rows2, cols2, vals2, spmm);

    attn_partial<<<dim3(512), dim3(256), 0, stream>>>(
        e, f, G_d, B_d, Pd, Qd, spmm, w_ae, w_af, partials);

    attn_final<<<dim3(1), dim3(128), 0, stream>>>(partials, b_ae, b_af, att);

    final_fused<<<dim3(NTOT/16), dim3(256), 0, stream>>>(
        e, f, G_d, B_d, Pd, Qd, spmm, att, W1, b1, W2, b2, (float*)d_out);
}